// Round 1
// baseline (7757.228 us; speedup 1.0000x reference)
//
#include <hip/hip_runtime.h>
#include <hip/hip_cooperative_groups.h>
#include <cstddef>

namespace cg = cooperative_groups;

// Problem constants (match reference)
constexpr int Bb = 16;
constexpr int Cc = 512;
constexpr int Kk = 32;
constexpr int Nn = 64 * 64;          // 4096 points per batch
constexpr int ITERS = 20;

// Launch geometry
constexpr int TPB  = 512;            // 8 waves
constexpr int PPB  = 256;            // points per block
constexpr int SUBS = Nn / PPB;       // 16 blocks per batch
constexpr int GRID = Bb * SUBS;      // 256 blocks (1 per CU)

static_assert(TPB == Cc, "B2 maps thread->column");

__global__ __launch_bounds__(TPB)
void kmeans_fused(const float* __restrict__ x, const int* __restrict__ idx,
                  float* __restrict__ out,
                  float* __restrict__ invn, float* __restrict__ cent,
                  float* __restrict__ psums, int* __restrict__ pcounts,
                  int* __restrict__ assign, int* __restrict__ flags)
{
    cg::grid_group gg = cg::this_grid();
    const int t   = threadIdx.x;
    const int bid = blockIdx.x;
    const int b   = bid / SUBS;
    const int sub = bid % SUBS;
    const int base = sub * PPB;

    __shared__ float s_sums[Kk][Cc];          // 64 KiB, aliased as scratch
    float* s_scratch = &s_sums[0][0];

    // ---------------- init: inverse norms (2 threads per point) ----------------
    {
        const int gtid = bid * TPB + t;       // 0..131071
        const int p    = gtid >> 1;           // global point id 0..65535
        const int half = gtid & 1;
        const float* xr = x + (size_t)p * Cc + half * (Cc / 2);
        float ss = 0.f;
        #pragma unroll
        for (int c0 = 0; c0 < Cc / 2; c0 += 4) {
            float4 v = *(const float4*)(xr + c0);
            ss = fmaf(v.x, v.x, fmaf(v.y, v.y, fmaf(v.z, v.z, fmaf(v.w, v.w, ss))));
        }
        ss += __shfl_xor(ss, 1);
        if (half == 0) invn[p] = 1.0f / fmaxf(sqrtf(ss), 1e-12f);
        if (gtid < ITERS) flags[gtid] = 0;    // clear change-flags (ws is poisoned)
    }
    gg.sync();

    // ---------------- init: gather + normalize initial centroids ----------------
    {
        const int gtid = bid * TPB + t;
        for (int e = gtid; e < Bb * Kk * Cc; e += GRID * TPB) {
            const int c  = e & (Cc - 1);
            const int bk = e >> 9;            // / 512
            const int k  = bk & (Kk - 1);
            const int bb = bk >> 5;           // / 32
            const int pid = idx[bb * Kk + k];
            cent[e] = x[((size_t)bb * Nn + pid) * Cc + c] * invn[bb * Nn + pid];
        }
    }
    gg.sync();

    const float* xb = x + (size_t)b * Nn * Cc;

    for (int it = 0; it < ITERS; ++it) {
        if (it > 0) {
            // No assignment changed last iteration => bit-exact fixed point; done.
            int ch = __hip_atomic_load(&flags[it - 1], __ATOMIC_RELAXED,
                                       __HIP_MEMORY_SCOPE_AGENT);
            if (ch == 0) break;               // uniform across grid
        }

        // ---------------- B phase: assign + partial sums ----------------
        if (t < Kk) pcounts[(sub * Bb + b) * Kk + t] = 0;

        // B1: similarities. Thread halves split K: kh in {0,1}, 16 centroids each.
        const int tp = t & (PPB - 1);
        const int kh = __builtin_amdgcn_readfirstlane(t >> 8);  // wave-uniform
        const int n  = base + tp;
        const float* xr = xb + (size_t)n * Cc;
        const float* cb = cent + ((size_t)b * Kk + kh * 16) * Cc;

        float sim[16];
        #pragma unroll
        for (int k = 0; k < 16; ++k) sim[k] = 0.f;

        for (int c0 = 0; c0 < Cc; c0 += 32) {
            float xv[32];
            #pragma unroll
            for (int j = 0; j < 32; j += 4)
                *(float4*)&xv[j] = *(const float4*)(xr + c0 + j);
            #pragma unroll
            for (int k = 0; k < 16; ++k) {
                #pragma unroll
                for (int j = 0; j < 32; ++j)
                    sim[k] = fmaf(xv[j], cb[k * Cc + c0 + j], sim[k]); // s_load bcast
            }
        }
        float best = sim[0]; int bk = 0;
        #pragma unroll
        for (int k = 1; k < 16; ++k)
            if (sim[k] > best) { best = sim[k]; bk = k; }   // strict > : first max

        // exchange upper half result via LDS scratch
        float* s_v = s_scratch;                 // [PPB]
        int*   s_i = (int*)(s_scratch + PPB);   // [PPB]
        if (kh == 1) { s_v[tp] = best; s_i[tp] = bk; }
        __syncthreads();
        if (kh == 0) {
            const float ub = s_v[tp];
            const int   ui = s_i[tp];
            const int amax = (ub > best) ? (16 + ui) : bk;  // tie -> lower k
            const int prev = assign[b * Nn + n];
            if (amax != prev) atomicOr(&flags[it], 1);
            assign[b * Nn + n] = amax;
            atomicAdd(&pcounts[(sub * Bb + b) * Kk + amax], 1);
        }
        __syncthreads();

        // zero LDS sums
        {
            const float4 z4 = make_float4(0.f, 0.f, 0.f, 0.f);
            #pragma unroll
            for (int e = 4 * t; e < Kk * Cc; e += 4 * TPB)
                *(float4*)(s_scratch + e) = z4;
        }
        __syncthreads();

        // B2: accumulate normalized points into LDS sums.
        // Thread t exclusively owns column t -> deterministic ds_add_f32,
        // bank = t%32 -> conflict-free.
        #pragma unroll 4
        for (int nn = 0; nn < PPB; ++nn) {
            const int   a  = assign[b * Nn + base + nn];  // uniform -> s_load
            const float sc = invn[b * Nn + base + nn];    // uniform -> s_load
            const float v  = xb[(size_t)(base + nn) * Cc + t];
            unsafeAtomicAdd(&s_sums[a][t], v * sc);
        }
        __syncthreads();

        // write partial sums (coalesced float4)
        {
            float* ps = psums + ((size_t)(sub * Bb + b) * Kk) * Cc;
            #pragma unroll
            for (int e = 4 * t; e < Kk * Cc; e += 4 * TPB)
                *(float4*)(ps + e) = *(const float4*)(s_scratch + e);
        }
        gg.sync();

        // ---------------- C phase: reduce partials + update centroids ----------------
        for (int ci = 2 * bid; ci < 2 * bid + 2; ++ci) {   // 512 centroids / 256 blocks
            float s = 0.f;
            #pragma unroll
            for (int sb = 0; sb < SUBS; ++sb)
                s += psums[((size_t)(sb * Bb) * Kk + ci) * Cc + t];
            int cnt = 0;
            #pragma unroll
            for (int sb = 0; sb < SUBS; ++sb)
                cnt += pcounts[sb * Bb * Kk + ci];         // uniform -> s_load

            float* crow = cent + (size_t)ci * Cc;
            const float m = (cnt > 0) ? (s / (float)cnt) : crow[t]; // empty: keep old

            // block-wide sum of m^2 (512 lanes)
            float ss = m * m;
            #pragma unroll
            for (int o = 32; o > 0; o >>= 1) ss += __shfl_down(ss, o, 64);
            if ((t & 63) == 0) s_scratch[t >> 6] = ss;
            __syncthreads();
            float tot = 0.f;
            #pragma unroll
            for (int w = 0; w < TPB / 64; ++w) tot += s_scratch[w];
            const float inv = 1.0f / fmaxf(sqrtf(tot), 1e-12f);
            crow[t] = m * inv;
            __syncthreads();
        }
        gg.sync();
    }

    // ---------------- output ----------------
    {
        const int gtid = bid * TPB + t;
        for (int e = gtid; e < Bb * Kk * Cc; e += GRID * TPB)
            out[e] = cent[e];
    }
}

extern "C" void kernel_launch(void* const* d_in, const int* in_sizes, int n_in,
                              void* d_out, int out_size, void* d_ws, size_t ws_size,
                              hipStream_t stream) {
    const float* x  = (const float*)d_in[0];
    const int* idx  = (const int*)d_in[1];
    float* out      = (float*)d_out;

    // workspace carve-up (~18.4 MiB total)
    char* ws = (char*)d_ws;
    size_t off = 0;
    float* invn    = (float*)(ws + off); off += (size_t)Bb * Nn * 4;            // 256 KiB
    float* cent    = (float*)(ws + off); off += (size_t)Bb * Kk * Cc * 4;       // 1 MiB
    float* psums   = (float*)(ws + off); off += (size_t)SUBS * Bb * Kk * Cc * 4;// 16 MiB
    int*   pcounts = (int*)  (ws + off); off += (size_t)SUBS * Bb * Kk * 4;     // 32 KiB
    int*   assign  = (int*)  (ws + off); off += (size_t)Bb * Nn * 4;            // 256 KiB
    int*   flags   = (int*)  (ws + off); off += (size_t)ITERS * 4;

    void* args[] = { (void*)&x, (void*)&idx, (void*)&out, (void*)&invn,
                     (void*)&cent, (void*)&psums, (void*)&pcounts,
                     (void*)&assign, (void*)&flags };
    hipLaunchCooperativeKernel((const void*)kmeans_fused, dim3(GRID), dim3(TPB),
                               args, 0, stream);
}

// Round 3
// 5098.903 us; speedup vs baseline: 1.5214x; 1.5214x over previous
//
#include <hip/hip_runtime.h>
#include <hip/hip_cooperative_groups.h>
#include <cstddef>

namespace cg = cooperative_groups;

// Problem constants (match reference)
constexpr int Bb = 16;
constexpr int Cc = 512;
constexpr int Kk = 32;
constexpr int Nn = 64 * 64;          // 4096 points per batch
constexpr int ITERS = 20;

// Launch geometry: 256 blocks x 512 threads, 1 block/CU.
constexpr int TPB  = 512;            // 8 waves
constexpr int PPB  = 256;            // points per block
constexpr int SUBS = Nn / PPB;       // 16 blocks per batch
constexpr int GRID = Bb * SUBS;      // 256 blocks

// fixed-point scale for deterministic (order-independent) i64 accumulation
constexpr float SCALE_F   = 1099511627776.0f;          // 2^40
constexpr float INVSCALE  = 1.0f / 1099511627776.0f;   // 2^-40

__global__ __launch_bounds__(TPB)
void kmeans_fused(const float* __restrict__ x, const int* __restrict__ idx,
                  float* __restrict__ out,
                  float* __restrict__ invn, float* __restrict__ cent,
                  long long* __restrict__ psums, int* __restrict__ pcounts,
                  int* __restrict__ assign, int* __restrict__ flags)
{
    cg::grid_group gg = cg::this_grid();
    const int t   = threadIdx.x;
    const int bid = blockIdx.x;
    const int b   = bid >> 4;            // bid / SUBS   (SUBS = 16)
    const int sub = bid & (SUBS - 1);
    const int base = sub * PPB;

    // ONE 64 KiB static LDS array (exactly 65536 B: proven-launchable size).
    // Regions (aliased, barrier-separated):
    //   B1 staging : s_buf[0..16383]           centroids [32][512] f32
    //   exchange   : floats [0..255]=s_v, ints [256..511]=s_i   (after barrier)
    //   B2 meta    : ints  [1024..1279]=s_asg, floats [1280..1535]=s_inv
    //   B2 sums    : bytes 8192..40959 = i64 [32][128]
    //   C reduce   : floats [10240..10247] = s_red
    __shared__ float s_buf[Kk * Cc];
    float*     s_v    = s_buf;
    int*       s_i    = (int*)(s_buf + 256);
    int*       s_asg  = (int*)(s_buf + 1024);
    float*     s_inv  = s_buf + 1280;
    long long* s_sums = (long long*)(s_buf + 2048);   // 4096 i64 = 32 KiB
    float*     s_red  = s_buf + 10240;

    // ---------------- init: inverse norms (2 threads per point) ----------------
    {
        const int gtid = bid * TPB + t;       // 0..131071
        const int p    = gtid >> 1;           // global point id 0..65535
        const int half = gtid & 1;
        const float* xr = x + (size_t)p * Cc + half * (Cc / 2);
        float ss = 0.f;
        #pragma unroll
        for (int c0 = 0; c0 < Cc / 2; c0 += 4) {
            float4 v = *(const float4*)(xr + c0);
            ss = fmaf(v.x, v.x, fmaf(v.y, v.y, fmaf(v.z, v.z, fmaf(v.w, v.w, ss))));
        }
        ss += __shfl_xor(ss, 1);
        if (half == 0) invn[p] = 1.0f / fmaxf(sqrtf(ss), 1e-12f);
        // zero deterministic accumulators + flags (ws is poisoned 0xAA)
        for (int e = gtid; e < Bb * Kk * Cc; e += GRID * TPB) psums[e] = 0;
        if (gtid < Bb * Kk) pcounts[gtid] = 0;
        if (gtid < ITERS)   flags[gtid] = 0;
    }
    gg.sync();

    // ---------------- init: gather + normalize initial centroids ----------------
    {
        const int gtid = bid * TPB + t;
        for (int e = gtid; e < Bb * Kk * Cc; e += GRID * TPB) {
            const int c  = e & (Cc - 1);
            const int bk = e >> 9;            // / 512
            const int k  = bk & (Kk - 1);
            const int bb = bk >> 5;           // / 32
            const int pid = idx[bb * Kk + k];
            cent[e] = x[((size_t)bb * Nn + pid) * Cc + c] * invn[bb * Nn + pid];
        }
    }
    gg.sync();

    const float* xb = x + (size_t)b * Nn * Cc;

    for (int it = 0; it < ITERS; ++it) {
        if (it > 0) {
            // No assignment changed last iteration => bit-exact fixed point.
            int ch = __hip_atomic_load(&flags[it - 1], __ATOMIC_RELAXED,
                                       __HIP_MEMORY_SCOPE_AGENT);
            if (ch == 0) break;               // uniform across grid
        }

        // ---------- stage centroids [32][512] into LDS (64 KiB) ----------
        {
            const float* cbp = cent + (size_t)b * Kk * Cc;
            #pragma unroll
            for (int e = 4 * t; e < Kk * Cc; e += 4 * TPB)   // 8 float4 each
                *(float4*)(s_buf + e) = *(const float4*)(cbp + e);
        }
        __syncthreads();

        // ---------- B1: similarities; halves split K (16 each) ----------
        const int tp = t & (PPB - 1);
        const int kh = t >> 8;                // waves 0-3 -> 0, waves 4-7 -> 1
        const int n  = base + tp;
        const float* xr = xb + (size_t)n * Cc;
        const float* cl = s_buf + kh * 16 * Cc;

        float sim[16];
        #pragma unroll
        for (int k = 0; k < 16; ++k) sim[k] = 0.f;

        // software-pipelined x stream (xva/xvb), c summed sequentially 0..511
        float xva[8], xvb[8];
        *(float4*)&xva[0] = *(const float4*)(xr);
        *(float4*)&xva[4] = *(const float4*)(xr + 4);
        for (int c0 = 0; c0 < Cc; c0 += 16) {
            *(float4*)&xvb[0] = *(const float4*)(xr + c0 + 8);
            *(float4*)&xvb[4] = *(const float4*)(xr + c0 + 12);
            #pragma unroll
            for (int k = 0; k < 16; ++k) {
                float cf[8];
                *(float4*)&cf[0] = *(const float4*)(cl + k * Cc + c0);     // bcast b128
                *(float4*)&cf[4] = *(const float4*)(cl + k * Cc + c0 + 4);
                #pragma unroll
                for (int j = 0; j < 8; ++j) sim[k] = fmaf(xva[j], cf[j], sim[k]);
            }
            if (c0 + 16 < Cc) {
                *(float4*)&xva[0] = *(const float4*)(xr + c0 + 16);
                *(float4*)&xva[4] = *(const float4*)(xr + c0 + 20);
            }
            #pragma unroll
            for (int k = 0; k < 16; ++k) {
                float cf[8];
                *(float4*)&cf[0] = *(const float4*)(cl + k * Cc + c0 + 8);
                *(float4*)&cf[4] = *(const float4*)(cl + k * Cc + c0 + 12);
                #pragma unroll
                for (int j = 0; j < 8; ++j) sim[k] = fmaf(xvb[j], cf[j], sim[k]);
            }
        }
        float best = sim[0]; int bki = 0;
        #pragma unroll
        for (int k = 1; k < 16; ++k)
            if (sim[k] > best) { best = sim[k]; bki = k; }  // strict > : first max

        __syncthreads();   // ALL centroid reads done -> s_buf reusable
        if (kh == 1) { s_v[tp] = best; s_i[tp] = bki; }
        __syncthreads();
        if (kh == 0) {
            const float ub = s_v[tp];
            const int   ui = s_i[tp];
            const int amax = (ub > best) ? (16 + ui) : bki; // tie -> lower k
            const int prev = assign[b * Nn + n];
            if (amax != prev) atomicOr(&flags[it], 1);
            assign[b * Nn + n] = amax;
            s_asg[tp] = amax;
            s_inv[tp] = invn[b * Nn + n];
            atomicAdd(&pcounts[b * Kk + amax], 1);
        }
        __syncthreads();

        // ---------- B2: deterministic i64 accumulation, 4 column passes ----------
        const int col_l = t & 127;
        const int h     = t >> 7;            // point-quarter 0..3 (wave-uniform)
        for (int pass = 0; pass < 4; ++pass) {
            for (int e = t; e < Kk * 128; e += TPB) s_sums[e] = 0;
            __syncthreads();
            const int col = pass * 128 + col_l;
            for (int j = 0; j < 64; ++j) {
                const int   p  = h * 64 + j;               // uniform per wave
                const int   a  = s_asg[p];                 // LDS broadcast
                const float sc = s_inv[p];
                const float v  = xb[(size_t)(base + p) * Cc + col]; // coalesced
                const long long q = (long long)(v * sc * SCALE_F);
                atomicAdd((unsigned long long*)&s_sums[a * 128 + col_l],
                          (unsigned long long)q);          // ds_add_u64, exact
            }
            __syncthreads();
            for (int e = t; e < Kk * 128; e += TPB) {      // 8 per thread
                const long long q = s_sums[e];
                if (q != 0) {
                    const int k = e >> 7;
                    const int c = (e & 127) + pass * 128;
                    atomicAdd((unsigned long long*)&psums[((size_t)b * Kk + k) * Cc + c],
                              (unsigned long long)q);      // exact integer add
                }
            }
            __syncthreads();
        }
        gg.sync();

        // ---------- C: finalize 2 centroids per block ----------
        for (int r = 0; r < 2; ++r) {
            const int ci = 2 * bid + r;                    // b*32 + k, 0..511
            const long long q = psums[(size_t)ci * Cc + t];
            const int cnt = pcounts[ci];                   // uniform
            const float s = (float)q * INVSCALE;
            float* crow = cent + (size_t)ci * Cc;
            const float m = (cnt > 0) ? (s / (float)cnt) : crow[t]; // empty: keep old
            float ss = m * m;
            #pragma unroll
            for (int o = 32; o > 0; o >>= 1) ss += __shfl_down(ss, o, 64);
            if ((t & 63) == 0) s_red[t >> 6] = ss;
            __syncthreads();
            float tot = 0.f;
            #pragma unroll
            for (int w = 0; w < TPB / 64; ++w) tot += s_red[w];
            crow[t] = m * (1.0f / fmaxf(sqrtf(tot), 1e-12f));
            // zero accumulators for next iteration (single owner -> race-free)
            psums[(size_t)ci * Cc + t] = 0;
            if (t == 0) pcounts[ci] = 0;
            __syncthreads();
        }
        gg.sync();
    }

    // ---------------- output ----------------
    {
        const int gtid = bid * TPB + t;
        for (int e = gtid; e < Bb * Kk * Cc; e += GRID * TPB)
            out[e] = cent[e];
    }
}

extern "C" void kernel_launch(void* const* d_in, const int* in_sizes, int n_in,
                              void* d_out, int out_size, void* d_ws, size_t ws_size,
                              hipStream_t stream) {
    const float* x  = (const float*)d_in[0];
    const int* idx  = (const int*)d_in[1];
    float* out      = (float*)d_out;

    // workspace carve-up (~3.5 MiB total; 8-byte-aligned region first)
    char* ws = (char*)d_ws;
    size_t off = 0;
    long long* psums = (long long*)(ws + off); off += (size_t)Bb * Kk * Cc * 8;  // 2 MiB
    float* invn      = (float*)(ws + off);     off += (size_t)Bb * Nn * 4;       // 256 KiB
    float* cent      = (float*)(ws + off);     off += (size_t)Bb * Kk * Cc * 4;  // 1 MiB
    int*   pcounts   = (int*)  (ws + off);     off += (size_t)Bb * Kk * 4;       // 2 KiB
    int*   assign    = (int*)  (ws + off);     off += (size_t)Bb * Nn * 4;       // 256 KiB
    int*   flags     = (int*)  (ws + off);     off += (size_t)ITERS * 4;

    void* args[] = { (void*)&x, (void*)&idx, (void*)&out, (void*)&invn,
                     (void*)&cent, (void*)&psums, (void*)&pcounts,
                     (void*)&assign, (void*)&flags };
    hipLaunchCooperativeKernel((const void*)kmeans_fused, dim3(GRID), dim3(TPB),
                               args, 0, stream);
}

// Round 7
// 3017.256 us; speedup vs baseline: 2.5710x; 1.6899x over previous
//
#include <hip/hip_runtime.h>
#include <hip/hip_cooperative_groups.h>
#include <cstddef>

namespace cg = cooperative_groups;

// Problem constants (match reference)
constexpr int Bb = 16;
constexpr int Cc = 512;
constexpr int Kk = 32;
constexpr int Nn = 64 * 64;          // 4096 points per batch
constexpr int ITERS = 20;

// Launch geometry: 256 blocks x 1024 threads (16 waves/CU, 4 waves/SIMD).
constexpr int TPB  = 1024;
constexpr int PPB  = 256;            // points per block (4 lanes per point)
constexpr int SUBS = Nn / PPB;       // 16 blocks per batch
constexpr int GRID = Bb * SUBS;      // 256 blocks

// fixed-point scale for deterministic (order-independent) i64 accumulation
constexpr float SCALE_F   = 1099511627776.0f;          // 2^40
constexpr float INVSCALE  = 1.0f / 1099511627776.0f;   // 2^-40

__global__ __launch_bounds__(TPB, 4)
void kmeans_fused(const float* __restrict__ x, const int* __restrict__ idx,
                  float* __restrict__ out,
                  float* __restrict__ invn, float* __restrict__ cent,
                  long long* __restrict__ psums, int* __restrict__ pcounts,
                  int* __restrict__ assign, int* __restrict__ flags)
{
    cg::grid_group gg = cg::this_grid();
    const int t   = threadIdx.x;
    const int bid = blockIdx.x;
    const int b   = bid >> 4;            // bid / SUBS (SUBS = 16)
    const int sub = bid & (SUBS - 1);
    const int base = sub * PPB;

    // ONE 64 KiB static LDS array. Regions (aliased, barrier-separated):
    //   B1: centroids [32][512] f32 (all 16384 floats)
    //   post-B1 meta: ints [1024..1279]=s_asg, [1280..1535]=s_old,
    //                 floats [1536..1791]=s_inv
    //   B2 sums: floats 2048..10239 = i64 [32][128] (32 KiB)
    //   C: floats [0..15] = s_red
    __shared__ float s_buf[Kk * Cc];
    int*       s_asg  = (int*)(s_buf + 1024);
    int*       s_old  = (int*)(s_buf + 1280);
    float*     s_inv  = s_buf + 1536;
    long long* s_sums = (long long*)(s_buf + 2048);
    float*     s_red  = s_buf;

    // ---------------- init: inverse norms (4 threads per point) ----------------
    {
        const int gtid = bid * TPB + t;       // 0..262143
        const int p    = gtid >> 2;           // global point id 0..65535
        const int qd   = gtid & 3;
        const float* xr = x + (size_t)p * Cc + qd * 128;
        float ss = 0.f;
        #pragma unroll
        for (int c0 = 0; c0 < 128; c0 += 4) {
            float4 v = *(const float4*)(xr + c0);
            ss = fmaf(v.x, v.x, fmaf(v.y, v.y, fmaf(v.z, v.z, fmaf(v.w, v.w, ss))));
        }
        ss += __shfl_xor(ss, 1);
        ss += __shfl_xor(ss, 2);
        if (qd == 0) invn[p] = 1.0f / fmaxf(sqrtf(ss), 1e-12f);
        // zero persistent accumulators + flags + assignments (ws poisoned 0xAA)
        for (int e = gtid; e < Bb * Kk * Cc; e += GRID * TPB) psums[e] = 0;
        if (gtid < Bb * Kk) pcounts[gtid] = 0;
        if (gtid < ITERS)   flags[gtid] = 0;
        for (int e = gtid; e < Bb * Nn; e += GRID * TPB) assign[e] = -1;
    }
    gg.sync();

    // ---------------- init: gather + normalize initial centroids ----------------
    {
        const int gtid = bid * TPB + t;
        for (int e = gtid; e < Bb * Kk * Cc; e += GRID * TPB) {
            const int c  = e & (Cc - 1);
            const int bk = e >> 9;            // / 512
            const int k  = bk & (Kk - 1);
            const int bb = bk >> 5;           // / 32
            const int pid = idx[bb * Kk + k];
            cent[e] = x[((size_t)bb * Nn + pid) * Cc + c] * invn[bb * Nn + pid];
        }
    }
    gg.sync();

    const float* xb = x + (size_t)b * Nn * Cc;

    for (int it = 0; it < ITERS; ++it) {
        if (it > 0) {
            // No assignment changed last iteration => bit-exact fixed point.
            int ch = __hip_atomic_load(&flags[it - 1], __ATOMIC_RELAXED,
                                       __HIP_MEMORY_SCOPE_AGENT);
            if (ch == 0) break;               // uniform across grid
        }

        // ---------- stage centroids [32][512] into LDS (64 KiB) ----------
        {
            const float* cbp = cent + (size_t)b * Kk * Cc;
            #pragma unroll
            for (int e = 4 * t; e < Kk * Cc; e += 4 * TPB)   // 4 float4 each
                *(float4*)(s_buf + e) = *(const float4*)(cbp + e);
        }
        __syncthreads();

        // ---------- B1: 4 lanes per point; lane covers channels (t&3)*4 + 16j ----
        const int p  = t >> 2;               // 0..255 (point within block)
        const int qo = (t & 3) * 4;          // quad channel offset
        const int n  = base + p;
        const float* xr = xb + (size_t)n * Cc;

        float sim[Kk];
        #pragma unroll
        for (int k = 0; k < Kk; ++k) sim[k] = 0.f;

        float4 xv = *(const float4*)(xr + qo);
        for (int c0 = 0; c0 < Cc; c0 += 16) {
            // prefetch next quad chunk (redundant re-load of chunk 0 at the end)
            const int cn = (c0 + 16 < Cc) ? (c0 + 16) : 0;
            const float4 xn = *(const float4*)(xr + cn + qo);
            const float* cl = s_buf + c0 + qo;
            #pragma unroll
            for (int k = 0; k < Kk; ++k) {
                const float4 cf = *(const float4*)(cl + k * Cc);  // 4-addr bcast b128
                sim[k] = fmaf(xv.x, cf.x,
                         fmaf(xv.y, cf.y,
                         fmaf(xv.z, cf.z,
                         fmaf(xv.w, cf.w, sim[k]))));
            }
            xv = xn;
        }
        // quad reduction: sim = l0+l1+l2+l3 (fixed order)
        #pragma unroll
        for (int k = 0; k < Kk; ++k) {
            sim[k] += __shfl_xor(sim[k], 1);
            sim[k] += __shfl_xor(sim[k], 2);
        }
        float best = sim[0]; int bki = 0;
        #pragma unroll
        for (int k = 1; k < Kk; ++k)
            if (sim[k] > best) { best = sim[k]; bki = k; }  // strict > : first max

        __syncthreads();   // ALL centroid reads done -> s_buf reusable

        if ((t & 3) == 0) {                   // quad leader owns the point
            const int prev = assign[b * Nn + n];
            if (bki != prev) {
                atomicOr(&flags[it], 1);
                atomicAdd(&pcounts[b * Kk + bki], 1);
                if (prev >= 0) atomicAdd(&pcounts[b * Kk + prev], -1);
                assign[b * Nn + n] = bki;
            }
            s_asg[p] = bki;
            s_old[p] = prev;
            s_inv[p] = invn[b * Nn + n];
        }
        __syncthreads();

        // ---------- B2: delta update of persistent i64 sums, 4 column passes ----
        // Only points whose assignment changed contribute (+q to new, -q to old).
        // Integer adds are exact => delta == full recompute, bit-identical.
        const int col_l = t & 127;
        const int h     = (t >> 7) & 7;      // 8 point-groups of 32 (wave-uniform)
        for (int pass = 0; pass < 4; ++pass) {
            for (int e = t; e < Kk * 128; e += TPB) s_sums[e] = 0;
            __syncthreads();
            const int col = pass * 128 + col_l;
            for (int j = 0; j < 32; ++j) {
                const int p2 = h * 32 + j;                 // uniform per wave
                const int a  = s_asg[p2];                  // LDS broadcast
                const int o  = s_old[p2];
                if (a == o) continue;                      // unchanged: skip
                const float sc = s_inv[p2];
                const float v  = xb[(size_t)(base + p2) * Cc + col]; // coalesced
                const long long q = (long long)(v * sc * SCALE_F);
                atomicAdd((unsigned long long*)&s_sums[a * 128 + col_l],
                          (unsigned long long)q);
                if (o >= 0)
                    atomicAdd((unsigned long long*)&s_sums[o * 128 + col_l],
                              (unsigned long long)(-q));
            }
            __syncthreads();
            for (int e = t; e < Kk * 128; e += TPB) {      // 4 per thread
                const long long q = s_sums[e];
                if (q != 0) {
                    const int k = e >> 7;
                    const int c = (e & 127) + pass * 128;
                    atomicAdd((unsigned long long*)&psums[((size_t)b * Kk + k) * Cc + c],
                              (unsigned long long)q);      // exact integer add
                }
            }
            __syncthreads();
        }
        gg.sync();

        // ---------- C: finalize 2 centroids per block (persistent sums) ----------
        for (int r = 0; r < 2; ++r) {
            const int ci = 2 * bid + r;                    // b*32 + k, 0..511
            float* crow = cent + (size_t)ci * Cc;
            float m = 0.f;
            if (t < Cc) {
                const long long q = psums[(size_t)ci * Cc + t];
                const int cnt = pcounts[ci];               // uniform
                const float s = (float)q * INVSCALE;
                m = (cnt > 0) ? (s / (float)cnt) : crow[t]; // empty: keep old
            }
            float ss = m * m;
            #pragma unroll
            for (int o = 32; o > 0; o >>= 1) ss += __shfl_down(ss, o, 64);
            if ((t & 63) == 0) s_red[t >> 6] = ss;
            __syncthreads();
            float tot = 0.f;
            #pragma unroll
            for (int w = 0; w < TPB / 64; ++w) tot += s_red[w];  // waves>=8 wrote 0
            if (t < Cc) crow[t] = m * (1.0f / fmaxf(sqrtf(tot), 1e-12f));
            __syncthreads();
        }
        gg.sync();
    }

    // ---------------- output ----------------
    {
        const int gtid = bid * TPB + t;
        for (int e = gtid; e < Bb * Kk * Cc; e += GRID * TPB)
            out[e] = cent[e];
    }
}

extern "C" void kernel_launch(void* const* d_in, const int* in_sizes, int n_in,
                              void* d_out, int out_size, void* d_ws, size_t ws_size,
                              hipStream_t stream) {
    const float* x  = (const float*)d_in[0];
    const int* idx  = (const int*)d_in[1];
    float* out      = (float*)d_out;

    // workspace carve-up (~3.5 MiB total; 8-byte-aligned region first)
    char* ws = (char*)d_ws;
    size_t off = 0;
    long long* psums = (long long*)(ws + off); off += (size_t)Bb * Kk * Cc * 8;  // 2 MiB
    float* invn      = (float*)(ws + off);     off += (size_t)Bb * Nn * 4;       // 256 KiB
    float* cent      = (float*)(ws + off);     off += (size_t)Bb * Kk * Cc * 4;  // 1 MiB
    int*   pcounts   = (int*)  (ws + off);     off += (size_t)Bb * Kk * 4;       // 2 KiB
    int*   assign    = (int*)  (ws + off);     off += (size_t)Bb * Nn * 4;       // 256 KiB
    int*   flags     = (int*)  (ws + off);     off += (size_t)ITERS * 4;

    void* args[] = { (void*)&x, (void*)&idx, (void*)&out, (void*)&invn,
                     (void*)&cent, (void*)&psums, (void*)&pcounts,
                     (void*)&assign, (void*)&flags };
    hipLaunchCooperativeKernel((const void*)kmeans_fused, dim3(GRID), dim3(TPB),
                               args, 0, stream);
}